// Round 2
// baseline (987.800 us; speedup 1.0000x reference)
//
#include <hip/hip_runtime.h>

// LocalSelfAttention (Swin-style windows, ws=8, nh=16, hd=32) with torch
// unfold+view scramble, B=16 N=4096 C=512.
// Buffers are FP32 (harness bf16-rounds values for comparison; 2% threshold).
// Compute path: fp32 -> bf16 (v_perm trunc, exact on bf16-grid inputs) ->
// mfma_f32_16x16x32_bf16 with fp32 accumulation -> fp32 stores.
//
// Index maps (algebraically verified against the reference):
//   xw[t, c] = x[bb, wh*512 + ((c%64)/8)*64 + ww*8 + (c%8),
//                 ch = (t%8)*64 + (t/8)*8 + c/64]
//   merge: o row t -> global token  bb*4096 + wh*512 + ww*8 + (t/8)*64 + (t%8)
//
// Kernel A: per-window gather + qkv GEMM + attention, o -> d_out (final rows, fp32).
// Kernel B: per-window proj GEMM + bias, in-place on d_out (rows window-exclusive).

typedef short s16x8 __attribute__((ext_vector_type(8)));
typedef float f32x4 __attribute__((ext_vector_type(4)));

union V8 {
    uint4  u4;
    uint2  u2[2];
    s16x8  h;
    ushort s[8];
    uint   u[4];
};

__device__ __forceinline__ ushort f2b(float f) {
    union { float f; uint u; } v; v.f = f;
    return (ushort)((v.u + 0x7fffu + ((v.u >> 16) & 1u)) >> 16);  // RNE
}
// 8 fp32 -> 8 bf16 by truncation (exact when inputs are bf16-grid fp32)
__device__ __forceinline__ void cvt8(const float* __restrict__ p, V8& d) {
    union { float4 f; uint u[4]; } a, b;
    a.f = *(const float4*)p;
    b.f = *(const float4*)(p + 4);
    d.u[0] = __builtin_amdgcn_perm(a.u[1], a.u[0], 0x07060302u);
    d.u[1] = __builtin_amdgcn_perm(a.u[3], a.u[2], 0x07060302u);
    d.u[2] = __builtin_amdgcn_perm(b.u[1], b.u[0], 0x07060302u);
    d.u[3] = __builtin_amdgcn_perm(b.u[3], b.u[2], 0x07060302u);
}
// 8 fp32 -> 8 bf16 RNE (for non-grid intermediate values)
__device__ __forceinline__ void cvt8r(const float* __restrict__ p, V8& d) {
    float4 a = *(const float4*)p, b = *(const float4*)(p + 4);
    d.s[0] = f2b(a.x); d.s[1] = f2b(a.y); d.s[2] = f2b(a.z); d.s[3] = f2b(a.w);
    d.s[4] = f2b(b.x); d.s[5] = f2b(b.y); d.s[6] = f2b(b.z); d.s[7] = f2b(b.w);
}
__device__ __forceinline__ f32x4 mfma16(s16x8 a, s16x8 b, f32x4 c) {
    return __builtin_amdgcn_mfma_f32_16x16x32_bf16(a, b, c, 0, 0, 0);
}

// ---------------------------------------------------------------------------
// Kernel A: gather + qkv + attention. 1 block = 1 window. 256 thr = 4 waves,
// each wave does 4 heads sequentially. LDS: xw 64K + 4*13.5K scratch = 118K.
// ---------------------------------------------------------------------------
__global__ __launch_bounds__(256, 1)
void win_attn_qkv(const float* __restrict__ x, const float* __restrict__ wqkv,
                  float* __restrict__ out)
{
    __shared__ ushort xw[64 * 512];      // A-tile (bf16), XOR-swizzled 8-elem chunks
    __shared__ ushort scr[4][6912];      // per-wave scratch (q/k then vT/P)

    const int tid  = threadIdx.x;
    const int lane = tid & 63;
    const int wave = tid >> 6;
    const int win  = blockIdx.x;
    const int bb = win >> 6, wh = (win >> 3) & 7, ww = win & 7;
    const size_t xbase = (size_t)(bb * 4096) * 512;
    const int colw = lane & 15;   // MFMA m/n lane index
    const int quad = lane >> 4;   // 0..3
    const int rowg = quad << 2;   // C-frag row group base
    const int kOff = quad << 3;   // A/B-frag k chunk base

    // ---------------- gather (scrambled window partition), fp32 -> bf16 ------
    {
        const int m8  = tid & 63;                       // channel-group id
        const int t   = ((m8 & 7) << 3) | (m8 >> 3);    // token this group maps to
        const int ch0 = m8 << 3;                        // 8 contiguous channels
        #pragma unroll
        for (int it = 0; it < 2; ++it) {
            const int u8 = (tid >> 6) + (it << 2);      // spatial row-in-window
            const float* gp = x + xbase + (size_t)(wh * 512 + u8 * 64 + ww * 8) * 512 + ch0;
            V8 L[8];
            #pragma unroll
            for (int du = 0; du < 8; ++du)              // 8 rows, 8 channels each
                cvt8(gp + du * 512, L[du]);
            #pragma unroll
            for (int e = 0; e < 8; ++e) {               // 8x8 in-register transpose
                V8 W;
                #pragma unroll
                for (int du = 0; du < 8; ++du) W.s[du] = L[du].s[e];
                const int c8 = (e << 3) | u8;           // chunk index in xw row
                *(uint4*)(&xw[(t << 9) + ((c8 ^ (t & 7)) << 3)]) = W.u4;
            }
        }
    }
    __syncthreads();

    ushort* const q_s = scr[wave];           // [64][40]   (phase 1)
    ushort* const k_s = scr[wave] + 2560;    // [64][40]   (phase 1)
    ushort* const vT  = scr[wave];           // [32][72]   (phase 2, overlays q)
    ushort* const P_s = scr[wave] + 2304;    // [64][72]   (phase 2)

    for (int hr = 0; hr < 4; ++hr) {
        const int h = (wave << 2) + hr;

        // ---------------- GEMM1: q,k,v (64x32 each) over K=512 ----------------
        f32x4 cq[4][2], ck[4][2], cv[4][2];
        #pragma unroll
        for (int mt = 0; mt < 4; ++mt)
            #pragma unroll
            for (int nt = 0; nt < 2; ++nt) {
                cq[mt][nt] = (f32x4){0.f,0.f,0.f,0.f};
                ck[mt][nt] = (f32x4){0.f,0.f,0.f,0.f};
                cv[mt][nt] = (f32x4){0.f,0.f,0.f,0.f};
            }
        const float* wq0 = wqkv + (size_t)(h * 32 + colw) * 512 + kOff;
        #pragma unroll 4
        for (int kk = 0; kk < 16; ++kk) {
            s16x8 a[4];
            #pragma unroll
            for (int mt = 0; mt < 4; ++mt) {
                const int m  = (mt << 4) | colw;
                const int c8 = (kk << 2) | quad;
                V8 v; v.u4 = *(const uint4*)(&xw[(m << 9) + ((c8 ^ (m & 7)) << 3)]);
                a[mt] = v.h;
            }
            #pragma unroll
            for (int nt = 0; nt < 2; ++nt) {
                const float* wp = wq0 + (size_t)(nt << 4) * 512 + (kk << 5);
                V8 bq, bk, bv;
                cvt8(wp,              bq);
                cvt8(wp + 512 * 512,  bk);
                cvt8(wp + 1024 * 512, bv);
                #pragma unroll
                for (int mt = 0; mt < 4; ++mt) {
                    cq[mt][nt] = mfma16(a[mt], bq.h, cq[mt][nt]);
                    ck[mt][nt] = mfma16(a[mt], bk.h, ck[mt][nt]);
                    cv[mt][nt] = mfma16(a[mt], bv.h, cv[mt][nt]);
                }
            }
        }

        // q,k C-frags -> LDS natural [t][d], stride 40
        #pragma unroll
        for (int mt = 0; mt < 4; ++mt)
            #pragma unroll
            for (int nt = 0; nt < 2; ++nt)
                #pragma unroll
                for (int r = 0; r < 4; ++r) {
                    const int t = (mt << 4) + rowg + r;
                    const int d = (nt << 4) + colw;
                    q_s[t * 40 + d] = f2b(cq[mt][nt][r]);
                    k_s[t * 40 + d] = f2b(ck[mt][nt][r]);
                }
        __syncthreads();

        // ---------------- S = q k^T  (K=32: one mfma per 16x16 tile) ----------
        s16x8 qa[4], kb[4];
        #pragma unroll
        for (int i = 0; i < 4; ++i) {
            const int rq = ((i << 4) + colw) * 40 + kOff;
            V8 va, vb;
            va.u2[0] = *(const uint2*)(&q_s[rq]);
            va.u2[1] = *(const uint2*)(&q_s[rq + 4]);
            vb.u2[0] = *(const uint2*)(&k_s[rq]);
            vb.u2[1] = *(const uint2*)(&k_s[rq + 4]);
            qa[i] = va.h; kb[i] = vb.h;
        }
        f32x4 S[4][4];
        #pragma unroll
        for (int mt = 0; mt < 4; ++mt)
            #pragma unroll
            for (int n2 = 0; n2 < 4; ++n2)
                S[mt][n2] = mfma16(qa[mt], kb[n2], (f32x4){0.f,0.f,0.f,0.f});

        // ---------------- softmax over key cols; rows fixed per (quad,reg) ----
        const float smul = 0.17677669529663689f * 1.4426950408889634f; // scale*log2e
        #pragma unroll
        for (int mt = 0; mt < 4; ++mt) {
            float mx[4], inv[4];
            #pragma unroll
            for (int c = 0; c < 4; ++c) {
                float m0 = fmaxf(fmaxf(S[mt][0][c], S[mt][1][c]),
                                 fmaxf(S[mt][2][c], S[mt][3][c]));
                m0 = fmaxf(m0, __shfl_xor(m0, 1));
                m0 = fmaxf(m0, __shfl_xor(m0, 2));
                m0 = fmaxf(m0, __shfl_xor(m0, 4));
                m0 = fmaxf(m0, __shfl_xor(m0, 8));
                mx[c] = m0;
            }
            float sum[4] = {0.f, 0.f, 0.f, 0.f};
            #pragma unroll
            for (int n2 = 0; n2 < 4; ++n2)
                #pragma unroll
                for (int c = 0; c < 4; ++c) {
                    const float p = exp2f((S[mt][n2][c] - mx[c]) * smul);
                    S[mt][n2][c] = p;
                    sum[c] += p;
                }
            #pragma unroll
            for (int c = 0; c < 4; ++c) {
                float s0 = sum[c];
                s0 += __shfl_xor(s0, 1);
                s0 += __shfl_xor(s0, 2);
                s0 += __shfl_xor(s0, 4);
                s0 += __shfl_xor(s0, 8);
                inv[c] = 1.0f / s0;
            }
            #pragma unroll
            for (int n2 = 0; n2 < 4; ++n2)
                #pragma unroll
                for (int c = 0; c < 4; ++c)
                    S[mt][n2][c] *= inv[c];
        }
        __syncthreads();   // q/k reads done before vT/P overlay writes

        // vT [32][72] (v^T for B-operand) and P [64][72] (A-operand)
        #pragma unroll
        for (int mt = 0; mt < 4; ++mt)
            #pragma unroll
            for (int nt = 0; nt < 2; ++nt)
                #pragma unroll
                for (int r = 0; r < 4; ++r) {
                    const int t = (mt << 4) + rowg + r;
                    const int d = (nt << 4) + colw;
                    vT[d * 72 + t] = f2b(cv[mt][nt][r]);
                }
        #pragma unroll
        for (int mt = 0; mt < 4; ++mt)
            #pragma unroll
            for (int n2 = 0; n2 < 4; ++n2)
                #pragma unroll
                for (int r = 0; r < 4; ++r) {
                    const int tq = (mt << 4) + rowg + r;
                    const int tk = (n2 << 4) + colw;
                    P_s[tq * 72 + tk] = f2b(S[mt][n2][r]);
                }
        __syncthreads();

        // ---------------- O = P v  (K=64: 2 k-steps) ----------------
        f32x4 O[4][2];
        #pragma unroll
        for (int mt = 0; mt < 4; ++mt)
            #pragma unroll
            for (int nt = 0; nt < 2; ++nt)
                O[mt][nt] = (f32x4){0.f,0.f,0.f,0.f};
        #pragma unroll
        for (int k2 = 0; k2 < 2; ++k2) {
            s16x8 pa[4], vb[2];
            #pragma unroll
            for (int mt = 0; mt < 4; ++mt) {
                V8 v; v.u4 = *(const uint4*)(&P_s[((mt << 4) + colw) * 72 + (k2 << 5) + kOff]);
                pa[mt] = v.h;
            }
            #pragma unroll
            for (int nt = 0; nt < 2; ++nt) {
                V8 v; v.u4 = *(const uint4*)(&vT[((nt << 4) + colw) * 72 + (k2 << 5) + kOff]);
                vb[nt] = v.h;
            }
            #pragma unroll
            for (int mt = 0; mt < 4; ++mt)
                #pragma unroll
                for (int nt = 0; nt < 2; ++nt)
                    O[mt][nt] = mfma16(pa[mt], vb[nt], O[mt][nt]);
        }

        // store o (fp32) at FINAL merged rows of d_out (window-exclusive rows)
        const size_t obase = (size_t)(bb * 4096 + wh * 512 + ww * 8) * 512 + h * 32;
        #pragma unroll
        for (int mt = 0; mt < 4; ++mt)
            #pragma unroll
            for (int nt = 0; nt < 2; ++nt)
                #pragma unroll
                for (int r = 0; r < 4; ++r) {
                    const int t = (mt << 4) + rowg + r;
                    const int goff = ((t >> 3) << 6) + (t & 7);   // p*64 + q
                    out[obase + (size_t)goff * 512 + (nt << 4) + colw] = O[mt][nt][r];
                }
        __syncthreads();   // protect scratch reuse by next head
    }
}

// ---------------------------------------------------------------------------
// Kernel B: per-window proj GEMM (64x512 @ 512x512^T) + bias, in-place fp32.
// ---------------------------------------------------------------------------
__global__ __launch_bounds__(256, 1)
void win_proj(const float* __restrict__ wproj, const float* __restrict__ bproj,
              float* __restrict__ out)
{
    __shared__ ushort ob[64 * 512];
    const int tid  = threadIdx.x;
    const int lane = tid & 63;
    const int wave = tid >> 6;
    const int win  = blockIdx.x;
    const int bb = win >> 6, wh = (win >> 3) & 7, ww = win & 7;
    const int colw = lane & 15, quad = lane >> 4;
    const int rowg = quad << 2, kOff = quad << 3;
    const size_t wbase = (size_t)(bb * 4096 + wh * 512 + ww * 8) * 512;

    // load this window's 64 rows of o (fp32) -> LDS bf16 (RNE; swizzled)
    {
        const int t  = tid >> 2;
        const int c0 = (tid & 3) << 7;
        const size_t rb = wbase + (size_t)(((t >> 3) << 6) + (t & 7)) * 512;
        #pragma unroll
        for (int i = 0; i < 16; ++i) {
            const int c = c0 + (i << 3);
            V8 v; cvt8r(out + rb + c, v);
            const int c8 = c >> 3;
            *(uint4*)(&ob[(t << 9) + ((c8 ^ (t & 7)) << 3)]) = v.u4;
        }
    }
    __syncthreads();

    f32x4 acc[4][8];
    #pragma unroll
    for (int mt = 0; mt < 4; ++mt)
        #pragma unroll
        for (int nt = 0; nt < 8; ++nt)
            acc[mt][nt] = (f32x4){0.f,0.f,0.f,0.f};

    const int nb = wave << 7;   // 128 output channels per wave
    #pragma unroll 2
    for (int kk = 0; kk < 16; ++kk) {
        s16x8 a[4];
        #pragma unroll
        for (int mt = 0; mt < 4; ++mt) {
            const int m  = (mt << 4) | colw;
            const int c8 = (kk << 2) | quad;
            V8 v; v.u4 = *(const uint4*)(&ob[(m << 9) + ((c8 ^ (m & 7)) << 3)]);
            a[mt] = v.h;
        }
        #pragma unroll
        for (int nt = 0; nt < 8; ++nt) {
            const int n = nb + (nt << 4) + colw;
            V8 b; cvt8(wproj + (size_t)n * 512 + (kk << 5) + kOff, b);
            #pragma unroll
            for (int mt = 0; mt < 4; ++mt)
                acc[mt][nt] = mfma16(a[mt], b.h, acc[mt][nt]);
        }
    }

    #pragma unroll
    for (int nt = 0; nt < 8; ++nt) {
        const float bias = bproj[nb + (nt << 4) + colw];
        #pragma unroll
        for (int mt = 0; mt < 4; ++mt)
            #pragma unroll
            for (int r = 0; r < 4; ++r) {
                const int t = (mt << 4) + rowg + r;
                const size_t go = wbase + (size_t)(((t >> 3) << 6) + (t & 7)) * 512;
                out[go + nb + (nt << 4) + colw] = acc[mt][nt][r] + bias;
            }
    }
}

extern "C" void kernel_launch(void* const* d_in, const int* in_sizes, int n_in,
                              void* d_out, int out_size, void* d_ws, size_t ws_size,
                              hipStream_t stream) {
    const float* x     = (const float*)d_in[0];
    const float* wqkv  = (const float*)d_in[1];
    const float* wproj = (const float*)d_in[2];
    const float* bproj = (const float*)d_in[3];
    float* out = (float*)d_out;
    (void)in_sizes; (void)n_in; (void)out_size; (void)d_ws; (void)ws_size;
    win_attn_qkv<<<dim3(1024), dim3(256), 0, stream>>>(x, wqkv, out);
    win_proj   <<<dim3(1024), dim3(256), 0, stream>>>(wproj, bproj, out);
}

// Round 3
// 604.958 us; speedup vs baseline: 1.6328x; 1.6328x over previous
//
#include <hip/hip_runtime.h>

// Fused LocalSelfAttention (Swin windows ws=8, nh=16, hd=32), B=16 N=4096 C=512.
// FP32 buffers; compute in bf16 MFMA w/ fp32 accum (harness threshold = 2%).
//
// Prologue: pack w_qkv + w_proj to bf16 in d_ws, pre-arranged in MFMA B-frag
// order so each weight load is one fully-coalesced 1KB/wave dwordx4.
// Fused kernel (512 thr, 1 window/block): gather -> qkv GEMM + attention
// (2 head-groups x 4 cooperative waves, per-head m-split) -> o tile in LDS ->
// proj GEMM + bias -> fp32 out at final merged positions.
// LDS: xw 64K + scr 2x13.5K + ob 64K = 155K -> 8 waves/CU (2/SIMD).

typedef short s16x8 __attribute__((ext_vector_type(8)));
typedef float f32x4 __attribute__((ext_vector_type(4)));

union V8 { uint4 u4; uint2 u2[2]; s16x8 h; ushort s[8]; uint u[4]; };

__device__ __forceinline__ ushort f2b(float f) {
    union { float f; uint u; } v; v.f = f;
    return (ushort)((v.u + 0x7fffu + ((v.u >> 16) & 1u)) >> 16);  // RNE
}
// 8 fp32 -> 8 bf16 truncation (1 v_perm per pair)
__device__ __forceinline__ void cvt8(const float* __restrict__ p, V8& d) {
    union { float4 f; uint u[4]; } a, b;
    a.f = *(const float4*)p;  b.f = *(const float4*)(p + 4);
    d.u[0] = __builtin_amdgcn_perm(a.u[1], a.u[0], 0x07060302u);
    d.u[1] = __builtin_amdgcn_perm(a.u[3], a.u[2], 0x07060302u);
    d.u[2] = __builtin_amdgcn_perm(b.u[1], b.u[0], 0x07060302u);
    d.u[3] = __builtin_amdgcn_perm(b.u[3], b.u[2], 0x07060302u);
}
__device__ __forceinline__ f32x4 mfma16(s16x8 a, s16x8 b, f32x4 c) {
    return __builtin_amdgcn_mfma_f32_16x16x32_bf16(a, b, c, 0, 0, 0);
}

// ---------------------------------------------------------------------------
// Prologue: fp32 weights -> bf16 in MFMA-fragment order.
// Layout (short units): tile = n-tile index (16 rows), per (tile,kk):
//   512-short block, element (quad*128 + colw*8 + j) = w[n=tile*16+colw][k=kk*32+quad*8+j]
// qkv: tiles 0..95 (mat*32 + ntile) at ws[0..786432); proj: tiles 0..31 at ws[786432..1048576)
// ---------------------------------------------------------------------------
__global__ __launch_bounds__(256)
void pack_w(const float* __restrict__ wqkv, const float* __restrict__ wproj,
            ushort* __restrict__ dst)
{
    const int gid = blockIdx.x * 256 + threadIdx.x;   // 131072 threads
    const int o = gid << 3;                           // short index in dst
    const int colw = (o >> 3) & 15, quad = (o >> 7) & 3, kk = (o >> 9) & 15;
    const int tile = o >> 13;
    const float* src;
    if (o < 786432) {
        const int mat = tile >> 5, nt = tile & 31;
        src = wqkv + (size_t)(mat * 512 + nt * 16 + colw) * 512 + (kk << 5) + (quad << 3);
    } else {
        const int nt = tile - 96;
        src = wproj + (size_t)(nt * 16 + colw) * 512 + (kk << 5) + (quad << 3);
    }
    float4 a = *(const float4*)src, b = *(const float4*)(src + 4);
    V8 v;
    v.s[0] = f2b(a.x); v.s[1] = f2b(a.y); v.s[2] = f2b(a.z); v.s[3] = f2b(a.w);
    v.s[4] = f2b(b.x); v.s[5] = f2b(b.y); v.s[6] = f2b(b.z); v.s[7] = f2b(b.w);
    *(uint4*)(dst + o) = v.u4;
}

// ---------------------------------------------------------------------------
// Fused kernel. PK=true: packed bf16 weights in ws. PK=false: fp32 fallback.
// ---------------------------------------------------------------------------
template<bool PK>
__global__ __launch_bounds__(512, 1)
void win_fused(const float* __restrict__ x, const void* __restrict__ Wq,
               const void* __restrict__ Wp, const float* __restrict__ bproj,
               float* __restrict__ out)
{
    __shared__ ushort xw[64 * 512];      // scrambled window A-tile (bf16, swizzled)
    __shared__ ushort scr[2][6912];      // per-head-group scratch (q/k then vT/P)
    __shared__ ushort ob[64 * 512];      // attention output tile (bf16, swizzled)

    const int tid  = threadIdx.x;
    const int lane = tid & 63;
    const int wave = tid >> 6;           // 0..7
    const int hg   = wave >> 2;          // head group 0/1
    const int wsub = wave & 3;           // m-stripe within group
    const int win  = blockIdx.x;
    const int bb = win >> 6, wh = (win >> 3) & 7, ww = win & 7;
    const int colw = lane & 15, quad = lane >> 4;
    const int rowg = quad << 2, kOff = quad << 3;
    const size_t xbase = (size_t)(bb * 4096) * 512;

    // ---------------- gather (scrambled window partition), fp32 -> bf16 ------
    {
        const int m8  = tid & 63;
        const int u8  = tid >> 6;                       // spatial row-in-window
        const int t   = ((m8 & 7) << 3) | (m8 >> 3);
        const int ch0 = m8 << 3;
        const float* gp = x + xbase + (size_t)(wh * 512 + u8 * 64 + ww * 8) * 512 + ch0;
        V8 L[8];
        #pragma unroll
        for (int du = 0; du < 8; ++du) cvt8(gp + du * 512, L[du]);
        #pragma unroll
        for (int e = 0; e < 8; ++e) {
            V8 W;
            #pragma unroll
            for (int du = 0; du < 8; ++du) W.s[du] = L[du].s[e];
            const int c8 = (e << 3) | u8;
            *(uint4*)(&xw[(t << 9) + ((c8 ^ (t & 7)) << 3)]) = W.u4;
        }
    }
    __syncthreads();

    ushort* const qg = scr[hg];          // [64][40]  phase 1
    ushort* const kg = scr[hg] + 2560;   // [64][40]  phase 1
    ushort* const vT = scr[hg];          // [32][72]  phase 2 (overlays q)
    ushort* const Ps = scr[hg] + 2304;   // [64][72]  phase 2

    for (int it = 0; it < 8; ++it) {
        const int h = (it << 1) | hg;

        // ---- GEMM1: q,k,v for this wave's 16-token stripe, K=512 ----
        f32x4 cq[2], ck[2], cv[2];
        #pragma unroll
        for (int nt = 0; nt < 2; ++nt) {
            cq[nt] = (f32x4){0.f,0.f,0.f,0.f};
            ck[nt] = (f32x4){0.f,0.f,0.f,0.f};
            cv[nt] = (f32x4){0.f,0.f,0.f,0.f};
        }
        #pragma unroll 4
        for (int kk = 0; kk < 16; ++kk) {
            const int m = (wsub << 4) | colw, c8 = (kk << 2) | quad;
            V8 av; av.u4 = *(const uint4*)(&xw[(m << 9) + ((c8 ^ (m & 7)) << 3)]);
            #pragma unroll
            for (int nt = 0; nt < 2; ++nt) {
                s16x8 bq, bk, bv;
                if constexpr (PK) {
                    const ushort* W = (const ushort*)Wq;
                    const size_t base = ((size_t)(((h << 1) | nt) << 4) + kk) * 512 + (lane << 3);
                    V8 q_, k_, v_;
                    q_.u4 = *(const uint4*)(&W[base]);
                    k_.u4 = *(const uint4*)(&W[base + 262144]);
                    v_.u4 = *(const uint4*)(&W[base + 524288]);
                    bq = q_.h; bk = k_.h; bv = v_.h;
                } else {
                    const float* W = (const float*)Wq;
                    const float* wp = W + (size_t)(h * 32 + (nt << 4) + colw) * 512 + (kk << 5) + kOff;
                    V8 q_, k_, v_;
                    cvt8(wp, q_); cvt8(wp + 512 * 512, k_); cvt8(wp + 1024 * 512, v_);
                    bq = q_.h; bk = k_.h; bv = v_.h;
                }
                cq[nt] = mfma16(av.h, bq, cq[nt]);
                ck[nt] = mfma16(av.h, bk, ck[nt]);
                cv[nt] = mfma16(av.h, bv, cv[nt]);
            }
        }

        // q,k stripes -> LDS [t][d], stride 40
        #pragma unroll
        for (int nt = 0; nt < 2; ++nt)
            #pragma unroll
            for (int r = 0; r < 4; ++r) {
                const int t = (wsub << 4) + rowg + r;
                const int d = (nt << 4) + colw;
                qg[t * 40 + d] = f2b(cq[nt][r]);
                kg[t * 40 + d] = f2b(ck[nt][r]);
            }
        __syncthreads();

        // ---- S stripe = q(16 tok) k^T(64 tok), K=32 ----
        V8 va;
        { const int rq = ((wsub << 4) + colw) * 40 + kOff;
          va.u2[0] = *(const uint2*)(&qg[rq]); va.u2[1] = *(const uint2*)(&qg[rq + 4]); }
        s16x8 kb[4];
        #pragma unroll
        for (int n2 = 0; n2 < 4; ++n2) {
            const int rk = ((n2 << 4) + colw) * 40 + kOff;
            V8 vb_; vb_.u2[0] = *(const uint2*)(&kg[rk]); vb_.u2[1] = *(const uint2*)(&kg[rk + 4]);
            kb[n2] = vb_.h;
        }
        f32x4 S[4];
        #pragma unroll
        for (int n2 = 0; n2 < 4; ++n2)
            S[n2] = mfma16(va.h, kb[n2], (f32x4){0.f,0.f,0.f,0.f});

        // ---- softmax over key cols ----
        const float smul = 0.17677669529663689f * 1.4426950408889634f;
        float mx[4], inv[4];
        #pragma unroll
        for (int c = 0; c < 4; ++c) {
            float m0 = fmaxf(fmaxf(S[0][c], S[1][c]), fmaxf(S[2][c], S[3][c]));
            m0 = fmaxf(m0, __shfl_xor(m0, 1));
            m0 = fmaxf(m0, __shfl_xor(m0, 2));
            m0 = fmaxf(m0, __shfl_xor(m0, 4));
            m0 = fmaxf(m0, __shfl_xor(m0, 8));
            mx[c] = m0;
        }
        float sum[4] = {0.f, 0.f, 0.f, 0.f};
        #pragma unroll
        for (int n2 = 0; n2 < 4; ++n2)
            #pragma unroll
            for (int c = 0; c < 4; ++c) {
                const float p = exp2f((S[n2][c] - mx[c]) * smul);
                S[n2][c] = p; sum[c] += p;
            }
        #pragma unroll
        for (int c = 0; c < 4; ++c) {
            float s0 = sum[c];
            s0 += __shfl_xor(s0, 1);
            s0 += __shfl_xor(s0, 2);
            s0 += __shfl_xor(s0, 4);
            s0 += __shfl_xor(s0, 8);
            inv[c] = 1.0f / s0;
        }
        #pragma unroll
        for (int n2 = 0; n2 < 4; ++n2)
            #pragma unroll
            for (int c = 0; c < 4; ++c) S[n2][c] *= inv[c];
        __syncthreads();   // q/k reads done before vT/P overlay

        // ---- vT [32][72] + P [64][72] ----
        #pragma unroll
        for (int nt = 0; nt < 2; ++nt)
            #pragma unroll
            for (int r = 0; r < 4; ++r) {
                const int t = (wsub << 4) + rowg + r;
                const int d = (nt << 4) + colw;
                vT[d * 72 + t] = f2b(cv[nt][r]);
            }
        #pragma unroll
        for (int n2 = 0; n2 < 4; ++n2)
            #pragma unroll
            for (int r = 0; r < 4; ++r) {
                const int tq = (wsub << 4) + rowg + r;
                const int tk = (n2 << 4) + colw;
                Ps[tq * 72 + tk] = f2b(S[n2][r]);
            }
        __syncthreads();

        // ---- O stripe = P v, K=64 ----
        f32x4 O[2] = {(f32x4){0.f,0.f,0.f,0.f}, (f32x4){0.f,0.f,0.f,0.f}};
        #pragma unroll
        for (int k2 = 0; k2 < 2; ++k2) {
            V8 pa; pa.u4 = *(const uint4*)(&Ps[((wsub << 4) + colw) * 72 + (k2 << 5) + kOff]);
            #pragma unroll
            for (int nt = 0; nt < 2; ++nt) {
                V8 vb_; vb_.u4 = *(const uint4*)(&vT[((nt << 4) + colw) * 72 + (k2 << 5) + kOff]);
                O[nt] = mfma16(pa.h, vb_.h, O[nt]);
            }
        }
        // o stripe -> ob (bf16, swizzled like xw)
        #pragma unroll
        for (int nt = 0; nt < 2; ++nt)
            #pragma unroll
            for (int r = 0; r < 4; ++r) {
                const int t = (wsub << 4) + rowg + r;
                const int c = (h << 5) + (nt << 4) + colw;
                ob[(t << 9) + (((c >> 3) ^ (t & 7)) << 3) + (c & 7)] = f2b(O[nt][r]);
            }
        __syncthreads();   // scr reuse next head; last iter: ob complete
    }

    // ---------------- proj GEMM: 64 x 512 @ 512x512^T + bias ----------------
    f32x4 acc[4][4];
    #pragma unroll
    for (int mt = 0; mt < 4; ++mt)
        #pragma unroll
        for (int nt = 0; nt < 4; ++nt) acc[mt][nt] = (f32x4){0.f,0.f,0.f,0.f};

    const int nb = wave << 6;   // 64 output cols per wave
    #pragma unroll 2
    for (int kk = 0; kk < 16; ++kk) {
        s16x8 a[4];
        #pragma unroll
        for (int mt = 0; mt < 4; ++mt) {
            const int m = (mt << 4) | colw, c8 = (kk << 2) | quad;
            V8 v; v.u4 = *(const uint4*)(&ob[(m << 9) + ((c8 ^ (m & 7)) << 3)]);
            a[mt] = v.h;
        }
        #pragma unroll
        for (int nt = 0; nt < 4; ++nt) {
            s16x8 b;
            if constexpr (PK) {
                const ushort* W = (const ushort*)Wp;
                const size_t base = ((size_t)((wave << 2) + nt) * 16 + kk) * 512 + (lane << 3);
                V8 v; v.u4 = *(const uint4*)(&W[base]); b = v.h;
            } else {
                const float* W = (const float*)Wp;
                V8 v; cvt8(W + (size_t)(nb + (nt << 4) + colw) * 512 + (kk << 5) + kOff, v);
                b = v.h;
            }
            #pragma unroll
            for (int mt = 0; mt < 4; ++mt)
                acc[mt][nt] = mfma16(a[mt], b, acc[mt][nt]);
        }
    }

    const size_t wbase = (size_t)(bb * 4096 + wh * 512 + ww * 8) * 512;
    #pragma unroll
    for (int nt = 0; nt < 4; ++nt) {
        const float bias = bproj[nb + (nt << 4) + colw];
        #pragma unroll
        for (int mt = 0; mt < 4; ++mt)
            #pragma unroll
            for (int r = 0; r < 4; ++r) {
                const int t = (mt << 4) + rowg + r;
                const size_t go = wbase + (size_t)(((t >> 3) << 6) + (t & 7)) * 512;
                out[go + nb + (nt << 4) + colw] = acc[mt][nt][r] + bias;
            }
    }
}

extern "C" void kernel_launch(void* const* d_in, const int* in_sizes, int n_in,
                              void* d_out, int out_size, void* d_ws, size_t ws_size,
                              hipStream_t stream) {
    const float* x     = (const float*)d_in[0];
    const float* wqkv  = (const float*)d_in[1];
    const float* wproj = (const float*)d_in[2];
    const float* bproj = (const float*)d_in[3];
    float* out = (float*)d_out;
    (void)in_sizes; (void)n_in; (void)out_size;

    if (ws_size >= 2097152) {
        ushort* wpk = (ushort*)d_ws;
        pack_w<<<dim3(512), dim3(256), 0, stream>>>(wqkv, wproj, wpk);
        win_fused<true><<<dim3(1024), dim3(512), 0, stream>>>(
            x, wpk, wpk + 786432, bproj, out);
    } else {
        win_fused<false><<<dim3(1024), dim3(512), 0, stream>>>(
            x, wqkv, wproj, bproj, out);
    }
}